// Round 6
// baseline (128.015 us; speedup 1.0000x reference)
//
#include <hip/hip_runtime.h>
#include <math.h>

#define NTH 512   // 8 waves; each thread owns 8 amps (3 register bits)

typedef float v4f __attribute__((ext_vector_type(4)));

// Storage swizzle: logical amp i lives at amp[Sw(i)] (bank spread).
__device__ __forceinline__ int Sw(int i) { return i ^ ((i >> 6) & 7); }

// CNOT-ring basis map (GF(2)-linear): state_after[Fr(i)] = state_before[i].
// Flat bit b holds qubit (11-b). Verified in R2/R4 kernels.
__device__ __forceinline__ int Fr(int i) {
    int x = i; x ^= x >> 1; x ^= x >> 2; x ^= x >> 4; x ^= x >> 8;
    return (x & 0x7FF) | (((x ^ (i >> 11)) & 1) << 11);
}

__device__ __forceinline__ float2 cmul(float2 a, float2 b) {
    return make_float2(a.x*b.x - a.y*b.y, a.x*b.y + a.y*b.x);
}

// Complex 2x2 gate rows u0,u1 = (u_r0,u_i0,u_r1,u_i1); v0 = bit-clear amp.
__device__ __forceinline__ void apply2(const float4 u0, const float4 u1,
                                       float2& v0, float2& v1) {
    const float n0r = u0.x*v0.x - u0.y*v0.y + u0.z*v1.x - u0.w*v1.y;
    const float n0i = u0.x*v0.y + u0.y*v0.x + u0.z*v1.y + u0.w*v1.x;
    const float n1r = u1.x*v0.x - u1.y*v0.y + u1.z*v1.x - u1.w*v1.y;
    const float n1i = u1.x*v0.y + u1.y*v0.x + u1.z*v1.y + u1.w*v1.x;
    v0 = make_float2(n0r, n0i);
    v1 = make_float2(n1r, n1i);
}

// Gate on register bit K of the 8-amp octet.
template<int K>
__device__ __forceinline__ void reg_gate(float2 v[8], const float4 u0,
                                         const float4 u1) {
    #pragma unroll
    for (int r = 0; r < 8; ++r)
        if (!(r & (1 << K))) apply2(u0, u1, v[r], v[r | (1 << K)]);
}

// Gate on lane bit LB (flat bit 3+LB in both layouts): wave-internal
// butterfly via shuffles — no LDS, no barrier.
template<int LB>
__device__ __forceinline__ void lane_gate(float2 v[8], const float4 u0,
                                          const float4 u1, const int lane) {
    const int mybit = (lane >> LB) & 1;
    const float4 rw = mybit ? u1 : u0;
    #pragma unroll
    for (int r = 0; r < 8; ++r) {
        float2 p;
        p.x = __shfl_xor(v[r].x, 1 << LB);
        p.y = __shfl_xor(v[r].y, 1 << LB);
        const float2 vc = mybit ? p : v[r];   // bit-clear amp
        const float2 vs = mybit ? v[r] : p;   // bit-set amp
        v[r] = make_float2(rw.x*vc.x - rw.y*vc.y + rw.z*vs.x - rw.w*vs.y,
                           rw.x*vc.y + rw.y*vc.x + rw.z*vs.y + rw.w*vs.x);
    }
}

// Layout A: logical i = (wave<<9)|(lane<<3)|r   (= (tid<<3)|r)
// Layout B: logical j = (r<<9)|(lane<<3)|wave
__global__ __launch_bounds__(NTH) void circuit_kernel(
    const float* __restrict__ qw,   // (3,12,3)
    const float* __restrict__ W1,   // (32,12)
    const float* __restrict__ b1,   // (32,)
    const float* __restrict__ W2,   // (16,32)
    const float* __restrict__ b2,   // (16,)
    float* __restrict__ pix)        // 16 outputs -> d_ws
{
    __shared__ float2 amp[4096];     // 32 KiB, swizzled storage
    __shared__ float4 gmat[36][2];   // U = RZ*RY*RX rows per gate
    __shared__ float  zp2[96];       // per-wave qubit partials (8 waves x 12)

    const int tid  = threadIdx.x;
    const int lane = tid & 63;
    const int wv   = tid >> 6;

    // ---- preload MLP weights early (latency hidden behind the circuit) ----
    float W1row[12], W2row[32], b1v = 0.f, b2v = 0.f;
    #pragma unroll
    for (int k = 0; k < 12; ++k) W1row[k] = 0.f;
    #pragma unroll
    for (int k = 0; k < 32; ++k) W2row[k] = 0.f;
    if (tid < 32) {
        b1v = b1[tid];
        #pragma unroll
        for (int k = 0; k < 12; ++k) W1row[k] = W1[tid*12 + k];
    }
    if (tid < 16) {
        b2v = b2[tid];
        #pragma unroll
        for (int k = 0; k < 32; ++k) W2row[k] = W2[tid*32 + k];
    }

    // ---- build the 36 gate matrices (one thread per gate) ----
    if (tid < 36) {
        float sx, cx, sy, cy, sz, cz;
        sincosf(0.5f * qw[tid*3+0], &sx, &cx);
        sincosf(0.5f * qw[tid*3+1], &sy, &cy);
        sincosf(0.5f * qw[tid*3+2], &sz, &cz);
        const float a00r =  cy*cx, a00i =  sy*sx;    // A = RY @ RX
        const float a01r = -sy*cx, a01i = -cy*sx;
        const float a10r =  sy*cx, a10i = -cy*sx;
        const float a11r =  cy*cx, a11i = -sy*sx;
        gmat[tid][0] = make_float4(cz*a00r + sz*a00i, cz*a00i - sz*a00r,
                                   cz*a01r + sz*a01i, cz*a01i - sz*a01r);
        gmat[tid][1] = make_float4(cz*a10r - sz*a10i, cz*a10i + sz*a10r,
                                   cz*a11r - sz*a11i, cz*a11i + sz*a11r);
    }
    __syncthreads();                                    // B1

    // ---- layer 1 = product state from |0..0>, built in registers; ring R1
    //      folded into the scatter write (verified in R4) ----
    {
        float2 pp = make_float2(1.f, 0.f);
        #pragma unroll
        for (int b = 11; b >= 3; --b) {                 // i bit b = tid bit b-3
            const int q = 11 - b;
            const float4 g = gmat[q][(tid >> (b - 3)) & 1];
            pp = cmul(pp, make_float2(g.x, g.y));       // column 0
        }
        float2 c9[2], c10[2], c11[2];
        #pragma unroll
        for (int s = 0; s < 2; ++s) {
            c9[s]  = make_float2(gmat[9][s].x,  gmat[9][s].y);
            c10[s] = make_float2(gmat[10][s].x, gmat[10][s].y);
            c11[s] = make_float2(gmat[11][s].x, gmat[11][s].y);
        }
        #pragma unroll
        for (int r = 0; r < 8; ++r) {
            const float2 v = cmul(pp,
                cmul(c9[(r>>2)&1], cmul(c10[(r>>1)&1], c11[r&1])));
            amp[Sw(Fr((tid << 3) | r))] = v;
        }
    }
    __syncthreads();                                    // B2

    float2 v[8];

    // ---- trip 1 (layout A): layer-2 gates on qubits 3..11 ----
    {
        #pragma unroll
        for (int r = 0; r < 8; ++r) v[r] = amp[Sw((tid << 3) | r)];
        lane_gate<5>(v, gmat[12+3][0], gmat[12+3][1], lane);   // q3
        lane_gate<4>(v, gmat[12+4][0], gmat[12+4][1], lane);   // q4
        lane_gate<3>(v, gmat[12+5][0], gmat[12+5][1], lane);   // q5
        lane_gate<2>(v, gmat[12+6][0], gmat[12+6][1], lane);   // q6
        lane_gate<1>(v, gmat[12+7][0], gmat[12+7][1], lane);   // q7
        lane_gate<0>(v, gmat[12+8][0], gmat[12+8][1], lane);   // q8
        reg_gate<2>(v, gmat[12+9][0],  gmat[12+9][1]);         // q9  (flat 2)
        reg_gate<1>(v, gmat[12+10][0], gmat[12+10][1]);        // q10 (flat 1)
        reg_gate<0>(v, gmat[12+11][0], gmat[12+11][1]);        // q11 (flat 0)
        #pragma unroll
        for (int r = 0; r < 8; ++r) amp[Sw((tid << 3) | r)] = v[r];  // in place
    }
    __syncthreads();                                    // B3

    // ---- trip 2 (layout B): layer-2 gates on qubits 0..2; ring R2 folded
    //      into the scatter write ----
    {
        #pragma unroll
        for (int r = 0; r < 8; ++r) v[r] = amp[Sw((r << 9) | (lane << 3) | wv)];
        reg_gate<2>(v, gmat[12+0][0], gmat[12+0][1]);          // q0 (flat 11)
        reg_gate<1>(v, gmat[12+1][0], gmat[12+1][1]);          // q1 (flat 10)
        reg_gate<0>(v, gmat[12+2][0], gmat[12+2][1]);          // q2 (flat 9)
        __syncthreads();                                // B4: reads done before scatter
        #pragma unroll
        for (int r = 0; r < 8; ++r)
            amp[Sw(Fr((r << 9) | (lane << 3) | wv))] = v[r];
    }
    __syncthreads();                                    // B5

    // ---- trip 3 (layout B): layer-3 gates on qubits 0..8 ----
    {
        #pragma unroll
        for (int r = 0; r < 8; ++r) v[r] = amp[Sw((r << 9) | (lane << 3) | wv)];
        reg_gate<2>(v, gmat[24+0][0], gmat[24+0][1]);          // q0
        reg_gate<1>(v, gmat[24+1][0], gmat[24+1][1]);          // q1
        reg_gate<0>(v, gmat[24+2][0], gmat[24+2][1]);          // q2
        lane_gate<5>(v, gmat[24+3][0], gmat[24+3][1], lane);   // q3
        lane_gate<4>(v, gmat[24+4][0], gmat[24+4][1], lane);   // q4
        lane_gate<3>(v, gmat[24+5][0], gmat[24+5][1], lane);   // q5
        lane_gate<2>(v, gmat[24+6][0], gmat[24+6][1], lane);   // q6
        lane_gate<1>(v, gmat[24+7][0], gmat[24+7][1], lane);   // q7
        lane_gate<0>(v, gmat[24+8][0], gmat[24+8][1], lane);   // q8
        #pragma unroll
        for (int r = 0; r < 8; ++r)
            amp[Sw((r << 9) | (lane << 3) | wv)] = v[r];       // in place
    }
    __syncthreads();                                    // B6

    // ---- trip 4 (layout A): layer-3 gates on qubits 9..11, then Z partials
    //      with ring R3 folded logically (no data movement; verified R4) ----
    float zacc[12];
    #pragma unroll
    for (int q = 0; q < 12; ++q) zacc[q] = 0.f;
    {
        #pragma unroll
        for (int r = 0; r < 8; ++r) v[r] = amp[Sw((tid << 3) | r)];
        reg_gate<2>(v, gmat[24+9][0],  gmat[24+9][1]);         // q9
        reg_gate<1>(v, gmat[24+10][0], gmat[24+10][1]);        // q10
        reg_gate<0>(v, gmat[24+11][0], gmat[24+11][1]);        // q11
        #pragma unroll
        for (int r = 0; r < 8; ++r) {
            const int x = Fr((tid << 3) | r);                  // final logical idx
            const float p = v[r].x*v[r].x + v[r].y*v[r].y;
            #pragma unroll
            for (int q = 0; q < 12; ++q)
                zacc[q] += ((x >> (11 - q)) & 1) ? -p : p;
        }
    }

    // ---- in-wave reduction (verified in R4) ----
    float z6[6];
    #pragma unroll
    for (int k = 0; k < 6; ++k) {
        const float send = (lane & 1) ? zacc[k]   : zacc[k+6];
        const float keep = (lane & 1) ? zacc[k+6] : zacc[k];
        z6[k] = keep + __shfl_xor(send, 1);
    }
    float z3[3];
    #pragma unroll
    for (int k = 0; k < 3; ++k) {
        const float send = (lane & 2) ? z6[k]   : z6[k+3];
        const float keep = (lane & 2) ? z6[k+3] : z6[k];
        z3[k] = keep + __shfl_xor(send, 2);
    }
    #pragma unroll
    for (int m = 4; m <= 32; m <<= 1) {
        #pragma unroll
        for (int k = 0; k < 3; ++k) z3[k] += __shfl_xor(z3[k], m);
    }
    if (lane < 4) {
        const int qb = 6*(lane & 1) + 3*((lane >> 1) & 1);
        #pragma unroll
        for (int k = 0; k < 3; ++k) zp2[wv*12 + qb + k] = z3[k];
    }
    __syncthreads();                                    // B7

    // ---- MLP entirely in wave 0 via shuffle broadcasts ----
    if (tid < 64) {
        float s = 0.f;
        if (tid < 12) {
            #pragma unroll
            for (int w8 = 0; w8 < 8; ++w8) s += zp2[w8*12 + tid];
        }
        float acc = b1v;                       // valid rows for lanes <32
        #pragma unroll
        for (int k = 0; k < 12; ++k) acc += W1row[k] * __shfl(s, k);
        const float h = acc > 0.f ? acc : 0.f;
        float acc2 = b2v;
        #pragma unroll
        for (int k = 0; k < 32; ++k) acc2 += W2row[k] * __shfl(h, k);
        if (tid < 16) pix[tid] = 1.f / (1.f + expf(-acc2));
    }
}

// ---------------------------------------------------------------------------
// Kernel B: broadcast 16 floats to (B,1,4,4) = 64 MiB, nontemporal stores
// via native clang vector type (HIP float4 is rejected by the builtin).
// ---------------------------------------------------------------------------
__global__ __launch_bounds__(256) void bcast_kernel(
    const v4f* __restrict__ pix4, v4f* __restrict__ out4)
{
    const int i = blockIdx.x * 256 + threadIdx.x;
    const v4f val = pix4[i & 3];
    __builtin_nontemporal_store(val, &out4[i]);
}

extern "C" void kernel_launch(void* const* d_in, const int* in_sizes, int n_in,
                              void* d_out, int out_size, void* d_ws, size_t ws_size,
                              hipStream_t stream) {
    // inputs: 0=images (ignored), 1=qweights, 2=W1, 3=b1, 4=W2, 5=b2
    const float* qw = (const float*)d_in[1];
    const float* W1 = (const float*)d_in[2];
    const float* b1 = (const float*)d_in[3];
    const float* W2 = (const float*)d_in[4];
    const float* b2 = (const float*)d_in[5];
    float* pix = (float*)d_ws;   // 16 floats of scratch

    circuit_kernel<<<1, NTH, 0, stream>>>(qw, W1, b1, W2, b2, pix);

    const int n4 = out_size / 4;               // 4,194,304 float4
    bcast_kernel<<<n4 / 256, 256, 0, stream>>>((const v4f*)pix,
                                               (v4f*)d_out);
}

// Round 7
// 123.274 us; speedup vs baseline: 1.0385x; 1.0385x over previous
//
#include <hip/hip_runtime.h>
#include <math.h>

#define NTH 512   // 8 waves; each thread owns an octet (8 amps = 3 qubits/pass)

typedef float v4f __attribute__((ext_vector_type(4)));

// Storage swizzle: logical amp i lives at amp[Sw(i)] (bank spread for the
// strided passes). Self-inverse on bits 0-2.
__device__ __forceinline__ int Sw(int i) { return i ^ ((i >> 6) & 7); }

// CNOT-ring basis map (GF(2)-linear): state_after[Fr(i)] = state_before[i].
// Flat bit b holds qubit (11-b). Verified R2/R4.
__device__ __forceinline__ int Fr(int i) {
    int x = i; x ^= x >> 1; x ^= x >> 2; x ^= x >> 4; x ^= x >> 8;
    return (x & 0x7FF) | (((x ^ (i >> 11)) & 1) << 11);
}

__device__ __forceinline__ float2 cmul(float2 a, float2 b) {
    return make_float2(a.x*b.x - a.y*b.y, a.x*b.y + a.y*b.x);
}

// Complex 2x2 gate, rows u0,u1 = (u_r0,u_i0,u_r1,u_i1); v0 = bit-clear amp.
__device__ __forceinline__ void apply2(const float4 u0, const float4 u1,
                                       float2& v0, float2& v1) {
    const float n0r = u0.x*v0.x - u0.y*v0.y + u0.z*v1.x - u0.w*v1.y;
    const float n0i = u0.x*v0.y + u0.y*v0.x + u0.z*v1.y + u0.w*v1.x;
    const float n1r = u1.x*v0.x - u1.y*v0.y + u1.z*v1.x - u1.w*v1.y;
    const float n1i = u1.x*v0.y + u1.y*v0.x + u1.z*v1.y + u1.w*v1.x;
    v0 = make_float2(n0r, n0i);
    v1 = make_float2(n1r, n1i);
}

// One LDS pass: 3 gates on flat bits PLOW+2..PLOW (qubits 9-PLOW..11-PLOW).
// MODE 0: in-place writeback. MODE 1: ring-fold scatter write (barrier first).
// MODE 2: no writeback — accumulate 12 signed probability partials using the
// ring-folded logical index. (All verified in R4.)
template<int PLOW, int MODE>
__device__ __forceinline__ void do_pass(float2* amp, const float4 (*gmat)[2],
                                        int gbase, int t, float* zacc) {
    int base;
    if      (PLOW == 9) base = t;
    else if (PLOW == 6) base = ((t >> 6) << 9) | (t & 63);
    else if (PLOW == 3) base = ((t >> 3) << 6) | (t & 7);
    else                base = t << 3;

    float2 v[8]; int idx[8];
    #pragma unroll
    for (int r = 0; r < 8; ++r) {
        idx[r] = Sw(base | (r << PLOW));
        v[r] = amp[idx[r]];
    }
    #pragma unroll
    for (int k = 2; k >= 0; --k) {
        const int q = 11 - (PLOW + k);          // qubit of flat bit PLOW+k
        const float4 u0 = gmat[gbase + q][0];
        const float4 u1 = gmat[gbase + q][1];
        const int m = 1 << k;
        #pragma unroll
        for (int r = 0; r < 8; ++r)
            if (!(r & m)) apply2(u0, u1, v[r], v[r | m]);
    }
    if (MODE == 0) {
        #pragma unroll
        for (int r = 0; r < 8; ++r) amp[idx[r]] = v[r];
    } else if (MODE == 1) {
        __syncthreads();   // all reads done before cross-thread scatter
        #pragma unroll
        for (int r = 0; r < 8; ++r) amp[Sw(Fr(base | (r << PLOW)))] = v[r];
    } else {
        #pragma unroll
        for (int r = 0; r < 8; ++r) {
            const int x = Fr(base | (r << PLOW));   // final logical index
            const float p = v[r].x*v[r].x + v[r].y*v[r].y;
            #pragma unroll
            for (int q = 0; q < 12; ++q)
                zacc[q] += ((x >> (11 - q)) & 1) ? -p : p;
        }
    }
}

__global__ __launch_bounds__(NTH) void circuit_kernel(
    const float* __restrict__ qw,   // (3,12,3)
    const float* __restrict__ W1,   // (32,12)
    const float* __restrict__ b1,   // (32,)
    const float* __restrict__ W2,   // (16,32)
    const float* __restrict__ b2,   // (16,)
    float* __restrict__ pix)        // 16 outputs -> d_ws
{
    __shared__ float2 amp[4096];     // 32 KiB, swizzled storage
    __shared__ float4 gmat[36][2];   // U = RZ*RY*RX rows per gate
    __shared__ float  zp2[96];       // per-wave qubit partials (8 waves x 12)

    const int tid  = threadIdx.x;
    const int lane = tid & 63;
    const int wv   = tid >> 6;

    // ---- preload MLP weights early (latency hidden behind the circuit) ----
    float W1row[12], W2row[32], b1v = 0.f, b2v = 0.f;
    #pragma unroll
    for (int k = 0; k < 12; ++k) W1row[k] = 0.f;
    #pragma unroll
    for (int k = 0; k < 32; ++k) W2row[k] = 0.f;
    if (tid < 32) {
        b1v = b1[tid];
        #pragma unroll
        for (int k = 0; k < 12; ++k) W1row[k] = W1[tid*12 + k];
    }
    if (tid < 16) {
        b2v = b2[tid];
        #pragma unroll
        for (int k = 0; k < 32; ++k) W2row[k] = W2[tid*32 + k];
    }

    // ---- build the 36 gate matrices (one thread per gate) ----
    if (tid < 36) {
        float sx, cx, sy, cy, sz, cz;
        sincosf(0.5f * qw[tid*3+0], &sx, &cx);
        sincosf(0.5f * qw[tid*3+1], &sy, &cy);
        sincosf(0.5f * qw[tid*3+2], &sz, &cz);
        const float a00r =  cy*cx, a00i =  sy*sx;    // A = RY @ RX
        const float a01r = -sy*cx, a01i = -cy*sx;
        const float a10r =  sy*cx, a10i = -cy*sx;
        const float a11r =  cy*cx, a11i = -sy*sx;
        gmat[tid][0] = make_float4(cz*a00r + sz*a00i, cz*a00i - sz*a00r,
                                   cz*a01r + sz*a01i, cz*a01i - sz*a01r);
        gmat[tid][1] = make_float4(cz*a10r - sz*a10i, cz*a10i + sz*a10r,
                                   cz*a11r - sz*a11i, cz*a11i + sz*a11r);
    }
    __syncthreads();

    // ---- layer 1 = product state from |0..0>, built in registers; ring R1
    //      folded into the scatter write (verified R4) ----
    {
        float2 pp = make_float2(1.f, 0.f);
        #pragma unroll
        for (int b = 11; b >= 3; --b) {                 // i bit b = tid bit b-3
            const int q = 11 - b;
            const float4 g = gmat[q][(tid >> (b - 3)) & 1];
            pp = cmul(pp, make_float2(g.x, g.y));       // column 0
        }
        float2 c9[2], c10[2], c11[2];
        #pragma unroll
        for (int s = 0; s < 2; ++s) {
            c9[s]  = make_float2(gmat[9][s].x,  gmat[9][s].y);
            c10[s] = make_float2(gmat[10][s].x, gmat[10][s].y);
            c11[s] = make_float2(gmat[11][s].x, gmat[11][s].y);
        }
        #pragma unroll
        for (int r = 0; r < 8; ++r) {
            const float2 v = cmul(pp,
                cmul(c9[(r>>2)&1], cmul(c10[(r>>1)&1], c11[r&1])));
            amp[Sw(Fr((tid << 3) | r))] = v;
        }
    }
    __syncthreads();

    float zacc[12];
    #pragma unroll
    for (int q = 0; q < 12; ++q) zacc[q] = 0.f;

    // ---- layer 2 (gates 12..23): 4 passes, ring folded into the last ----
    do_pass<9,0>(amp, gmat, 12, tid, zacc); __syncthreads();
    do_pass<6,0>(amp, gmat, 12, tid, zacc); __syncthreads();
    do_pass<3,0>(amp, gmat, 12, tid, zacc); __syncthreads();
    do_pass<0,1>(amp, gmat, 12, tid, zacc); __syncthreads();
    // ---- layer 3 (gates 24..35): last pass emits partials, no writeback ----
    do_pass<9,0>(amp, gmat, 24, tid, zacc); __syncthreads();
    do_pass<6,0>(amp, gmat, 24, tid, zacc); __syncthreads();
    do_pass<3,0>(amp, gmat, 24, tid, zacc); __syncthreads();
    do_pass<0,2>(amp, gmat, 24, tid, zacc);

    // ---- in-wave reduction (verified R4) ----
    float z6[6];
    #pragma unroll
    for (int k = 0; k < 6; ++k) {
        const float send = (lane & 1) ? zacc[k]   : zacc[k+6];
        const float keep = (lane & 1) ? zacc[k+6] : zacc[k];
        z6[k] = keep + __shfl_xor(send, 1);
    }
    float z3[3];
    #pragma unroll
    for (int k = 0; k < 3; ++k) {
        const float send = (lane & 2) ? z6[k]   : z6[k+3];
        const float keep = (lane & 2) ? z6[k+3] : z6[k];
        z3[k] = keep + __shfl_xor(send, 2);
    }
    #pragma unroll
    for (int m = 4; m <= 32; m <<= 1) {
        #pragma unroll
        for (int k = 0; k < 3; ++k) z3[k] += __shfl_xor(z3[k], m);
    }
    if (lane < 4) {
        const int qb = 6*(lane & 1) + 3*((lane >> 1) & 1);
        #pragma unroll
        for (int k = 0; k < 3; ++k) zp2[wv*12 + qb + k] = z3[k];
    }
    __syncthreads();

    // ---- MLP entirely in wave 0 via shuffle broadcasts (verified R6) ----
    if (tid < 64) {
        float s = 0.f;
        if (tid < 12) {
            #pragma unroll
            for (int w8 = 0; w8 < 8; ++w8) s += zp2[w8*12 + tid];
        }
        float acc = b1v;                       // valid rows for lanes <32
        #pragma unroll
        for (int k = 0; k < 12; ++k) acc += W1row[k] * __shfl(s, k);
        const float h = acc > 0.f ? acc : 0.f;
        float acc2 = b2v;
        #pragma unroll
        for (int k = 0; k < 32; ++k) acc2 += W2row[k] * __shfl(h, k);
        if (tid < 16) pix[tid] = 1.f / (1.f + expf(-acc2));
    }
}

// ---------------------------------------------------------------------------
// Kernel B: broadcast 16 floats to (B,1,4,4) = 64 MiB, nontemporal stores
// via native clang vector type (HIP float4 is rejected by the builtin).
// ---------------------------------------------------------------------------
__global__ __launch_bounds__(256) void bcast_kernel(
    const v4f* __restrict__ pix4, v4f* __restrict__ out4)
{
    const int i = blockIdx.x * 256 + threadIdx.x;
    const v4f val = pix4[i & 3];
    __builtin_nontemporal_store(val, &out4[i]);
}

extern "C" void kernel_launch(void* const* d_in, const int* in_sizes, int n_in,
                              void* d_out, int out_size, void* d_ws, size_t ws_size,
                              hipStream_t stream) {
    // inputs: 0=images (ignored), 1=qweights, 2=W1, 3=b1, 4=W2, 5=b2
    const float* qw = (const float*)d_in[1];
    const float* W1 = (const float*)d_in[2];
    const float* b1 = (const float*)d_in[3];
    const float* W2 = (const float*)d_in[4];
    const float* b2 = (const float*)d_in[5];
    float* pix = (float*)d_ws;   // 16 floats of scratch

    circuit_kernel<<<1, NTH, 0, stream>>>(qw, W1, b1, W2, b2, pix);

    const int n4 = out_size / 4;               // 4,194,304 float4
    bcast_kernel<<<n4 / 256, 256, 0, stream>>>((const v4f*)pix,
                                               (v4f*)d_out);
}